// Round 2
// baseline (1317.369 us; speedup 1.0000x reference)
//
#include <hip/hip_runtime.h>
#include <hip/hip_bf16.h>
#include <math.h>

#define EPSF 1e-7f
#define MAXT 0.99999f   // 1 - 1e-5

constexpr int Bb = 2048;
constexpr int Ss = 768;
constexpr int Dd = 128;
constexpr int Nn = 100000;
constexpr int Kk = 5;
constexpr int HALF = Bb * Dd;        // 262144
constexpr int NCHUNK = 16;
constexpr int CHUNK = Nn / NCHUNK;   // 6250
constexpr int RT = 128;              // rows per topk block
constexpr int NT = 128;              // nodes per tile
constexpr int LDZ = 132;             // padded LDS leading dim (float4-aligned)

// Insert into ascending-sorted top-5 (strict <: stable, keeps earlier/lower idx on tie).
#define INS5(TV, TI, V, ID) do { \
  const float _v = (V); const int _id = (ID); \
  if (_v < TV[4]) { \
    TV[4] = _v; TI[4] = _id; \
    if (TV[4] < TV[3]) { float _t=TV[3];TV[3]=TV[4];TV[4]=_t;int _u=TI[3];TI[3]=TI[4];TI[4]=_u; } \
    if (TV[3] < TV[2]) { float _t=TV[2];TV[2]=TV[3];TV[3]=_t;int _u=TI[2];TI[2]=TI[3];TI[3]=_u; } \
    if (TV[2] < TV[1]) { float _t=TV[1];TV[1]=TV[2];TV[2]=_t;int _u=TI[1];TI[1]=TI[2];TI[2]=_u; } \
    if (TV[1] < TV[0]) { float _t=TV[0];TV[0]=TV[1];TV[1]=_t;int _u=TI[0];TI[0]=TI[1];TI[1]=_u; } \
  } } while(0)

// Lexicographic (value, index) insert for merging unordered candidate streams.
#define LXLT(V,I,V2,I2) ((V) < (V2) || ((V) == (V2) && (I) < (I2)))
#define INS5L(TV, TI, V, ID) do { \
  const float _v = (V); const int _id = (ID); \
  if (LXLT(_v,_id,TV[4],TI[4])) { \
    TV[4]=_v; TI[4]=_id; \
    if (LXLT(TV[4],TI[4],TV[3],TI[3])) { float _t=TV[3];TV[3]=TV[4];TV[4]=_t;int _u=TI[3];TI[3]=TI[4];TI[4]=_u; } \
    if (LXLT(TV[3],TI[3],TV[2],TI[2])) { float _t=TV[2];TV[2]=TV[3];TV[3]=_t;int _u=TI[2];TI[2]=TI[3];TI[3]=_u; } \
    if (LXLT(TV[2],TI[2],TV[1],TI[1])) { float _t=TV[1];TV[1]=TV[2];TV[2]=_t;int _u=TI[1];TI[1]=TI[2];TI[2]=_u; } \
    if (LXLT(TV[1],TI[1],TV[0],TI[0])) { float _t=TV[0];TV[0]=TV[1];TV[1]=_t;int _u=TI[0];TI[0]=TI[1];TI[1]=_u; } \
  } } while(0)

// Kernel 1: z_proj = z_seq @ W.T + b; z_hyp = expmap0(z_proj) -> out[HALF..] (f32);
// z_tan = logmap0(z_hyp) -> ws. 8 rows per block, 128 threads (thread = dim d).
__global__ __launch_bounds__(128) void k_proj(
    const float* __restrict__ zseq, const float* __restrict__ W,
    const float* __restrict__ bias, float* __restrict__ outH,
    float* __restrict__ zt)
{
  __shared__ __align__(16) float zrow[8][768];
  __shared__ float zp[8][128];
  __shared__ float rno[8];
  const int tid = threadIdx.x;
  const int r0 = blockIdx.x * 8;

  {
    const float4* src = reinterpret_cast<const float4*>(zseq + (size_t)r0 * Ss);
    float4* dst = reinterpret_cast<float4*>(&zrow[0][0]);
    #pragma unroll
    for (int i = 0; i < 12; ++i) dst[i * 128 + tid] = src[i * 128 + tid];
  }
  __syncthreads();

  float acc[8];
  const float bv = bias[tid];
  #pragma unroll
  for (int r = 0; r < 8; ++r) acc[r] = bv;
  const float4* w4 = reinterpret_cast<const float4*>(W + (size_t)tid * Ss);
  for (int j = 0; j < Ss / 4; ++j) {
    const float4 w = w4[j];
    #pragma unroll
    for (int r = 0; r < 8; ++r) {
      const float4 z = *reinterpret_cast<const float4*>(&zrow[r][j * 4]);
      acc[r] = fmaf(z.x, w.x, acc[r]);
      acc[r] = fmaf(z.y, w.y, acc[r]);
      acc[r] = fmaf(z.z, w.z, acc[r]);
      acc[r] = fmaf(z.w, w.w, acc[r]);
    }
  }
  #pragma unroll
  for (int r = 0; r < 8; ++r) zp[r][tid] = acc[r];
  __syncthreads();

  const int wv = tid >> 6, ln = tid & 63;
  #pragma unroll
  for (int rr = 0; rr < 4; ++rr) {
    const int r = wv * 4 + rr;
    float v = zp[r][ln] * zp[r][ln] + zp[r][ln + 64] * zp[r][ln + 64];
    #pragma unroll
    for (int off = 32; off > 0; off >>= 1) v += __shfl_xor(v, off);
    if (ln == 0) rno[r] = v;
  }
  __syncthreads();

  #pragma unroll
  for (int r = 0; r < 8; ++r) {
    const float n = fmaxf(sqrtf(rno[r]), EPSF);
    const float zh = tanhf(n) * zp[r][tid] / n;
    outH[(size_t)(r0 + r) * Dd + tid] = zh;   // z_hyp output (f32)
    zp[r][tid] = zh;
  }
  __syncthreads();
  #pragma unroll
  for (int rr = 0; rr < 4; ++rr) {
    const int r = wv * 4 + rr;
    float v = zp[r][ln] * zp[r][ln] + zp[r][ln + 64] * zp[r][ln + 64];
    #pragma unroll
    for (int off = 32; off > 0; off >>= 1) v += __shfl_xor(v, off);
    if (ln == 0) rno[r] = v;
  }
  __syncthreads();
  #pragma unroll
  for (int r = 0; r < 8; ++r) {
    const float m = fmaxf(sqrtf(rno[r]), EPSF);
    const float a = atanhf(fminf(m, MAXT));
    zt[(size_t)(r0 + r) * Dd + tid] = a * zp[r][tid] / m;
  }
}

// Kernel 2: per-node logmap0 scalars: s_n = atanh(clip(||e||))/||e||, c_n = ||n_tan||^2.
// One wave per node (64 lanes x float2 = 128 dims), 4 nodes/block.
__global__ __launch_bounds__(256) void k_node(
    const float* __restrict__ emb, float* __restrict__ sArr, float* __restrict__ cArr)
{
  const int wv = threadIdx.x >> 6, ln = threadIdx.x & 63;
  const int node = blockIdx.x * 4 + wv;
  const float2 v = *reinterpret_cast<const float2*>(emb + (size_t)node * Dd + ln * 2);
  float t = v.x * v.x + v.y * v.y;
  #pragma unroll
  for (int off = 32; off > 0; off >>= 1) t += __shfl_xor(t, off);
  if (ln == 0) {
    const float E = fmaxf(sqrtf(t), EPSF);
    const float a = atanhf(fminf(E, MAXT));
    const float s = a / E;
    sArr[node] = s;
    cArr[node] = s * s * t;
  }
}

// Kernel 3: fused score-GEMM + top-5. Block = 128 rows x 6250-node chunk.
// score_n = c_n - 2*s_n*(z_tan . emb_n)  (same ranking as reference d2).
__global__ __launch_bounds__(256, 1) void k_topk(
    const float* __restrict__ zt, const float* __restrict__ emb,
    const float* __restrict__ sArr, const float* __restrict__ cArr,
    float* __restrict__ candV, int* __restrict__ candI)
{
  __shared__ __align__(16) float smem[2 * 128 * LDZ + 2 * NT];  // zs | es | sl | cl
  float* zs = smem;
  float* es = smem + 128 * LDZ;
  float* sl = smem + 2 * 128 * LDZ;
  float* cl = sl + NT;

  const int tid = threadIdx.x;
  const int ty = tid >> 4;      // 16 row groups of 8
  const int tx = tid & 15;      // 16 node groups of 8
  const int rowBase = blockIdx.x * RT;
  const int chunkStart = blockIdx.y * CHUNK;

  // stage z tile transposed to [k][row]
  #pragma unroll
  for (int i = 0; i < 16; ++i) {
    const int f = i * 256 + tid;
    const int row = f >> 5, k4 = f & 31;
    const float4 v = *reinterpret_cast<const float4*>(
        zt + (size_t)(rowBase + row) * Dd + k4 * 4);
    zs[(k4 * 4 + 0) * LDZ + row] = v.x;
    zs[(k4 * 4 + 1) * LDZ + row] = v.y;
    zs[(k4 * 4 + 2) * LDZ + row] = v.z;
    zs[(k4 * 4 + 3) * LDZ + row] = v.w;
  }

  float tv[8][5]; int ti[8][5];
  #pragma unroll
  for (int r = 0; r < 8; ++r)
    #pragma unroll
    for (int q = 0; q < 5; ++q) { tv[r][q] = 3.0e38f; ti[r][q] = 0x7fffffff; }

  float acc[8][8];
  #pragma unroll
  for (int r = 0; r < 8; ++r)
    #pragma unroll
    for (int c = 0; c < 8; ++c) acc[r][c] = 0.f;

  constexpr int nTiles = (CHUNK + NT - 1) / NT;   // 49 (last tile: 106 nodes)
  for (int tile = 0; tile < nTiles; ++tile) {
    const int tStart = tile * NT;
    const int left = CHUNK - tStart;
    __syncthreads();
    // stage emb tile transposed to [k][node]; pad invalid nodes with 0 / +inf score
    #pragma unroll
    for (int i = 0; i < 16; ++i) {
      const int f = i * 256 + tid;
      const int nd = f >> 5, k4 = f & 31;
      float4 v = make_float4(0.f, 0.f, 0.f, 0.f);
      if (nd < left)
        v = *reinterpret_cast<const float4*>(
            emb + (size_t)(chunkStart + tStart + nd) * Dd + k4 * 4);
      es[(k4 * 4 + 0) * LDZ + nd] = v.x;
      es[(k4 * 4 + 1) * LDZ + nd] = v.y;
      es[(k4 * 4 + 2) * LDZ + nd] = v.z;
      es[(k4 * 4 + 3) * LDZ + nd] = v.w;
    }
    if (tid < NT) {
      const bool ok = tid < left;
      sl[tid] = ok ? sArr[chunkStart + tStart + tid] : 0.f;
      cl[tid] = ok ? cArr[chunkStart + tStart + tid] : 3.0e38f;
    }
    __syncthreads();

    #pragma unroll 4
    for (int k = 0; k < Dd; ++k) {
      const float4 za = *reinterpret_cast<const float4*>(zs + k * LDZ + ty * 8);
      const float4 zb = *reinterpret_cast<const float4*>(zs + k * LDZ + ty * 8 + 4);
      const float4 ea = *reinterpret_cast<const float4*>(es + k * LDZ + tx * 8);
      const float4 eb = *reinterpret_cast<const float4*>(es + k * LDZ + tx * 8 + 4);
      const float zr[8] = {za.x, za.y, za.z, za.w, zb.x, zb.y, zb.z, zb.w};
      const float ec[8] = {ea.x, ea.y, ea.z, ea.w, eb.x, eb.y, eb.z, eb.w};
      #pragma unroll
      for (int r = 0; r < 8; ++r)
        #pragma unroll
        for (int c = 0; c < 8; ++c)
          acc[r][c] = fmaf(zr[r], ec[c], acc[r][c]);
    }

    // epilogue: scores + top-5 update (node idx strictly increasing per thread)
    #pragma unroll
    for (int c = 0; c < 8; ++c) {
      const int lc = tx * 8 + c;
      const float sv = sl[lc];
      const float cv = cl[lc];
      const int node = chunkStart + tStart + lc;
      #pragma unroll
      for (int r = 0; r < 8; ++r) {
        const float sc_ = fmaf(-2.f * sv, acc[r][c], cv);
        acc[r][c] = 0.f;
        INS5(tv[r], ti[r], sc_, node);
      }
    }
  }

  // merge 16 per-thread top-5 lists per row -> per-(row,chunk) top-5 in ws
  __syncthreads();
  float* cvB = smem;                                    // 128*16*5 floats
  int* ciB = reinterpret_cast<int*>(smem + 128 * 16 * 5);
  #pragma unroll
  for (int r = 0; r < 8; ++r) {
    const int row = ty * 8 + r;
    #pragma unroll
    for (int q = 0; q < 5; ++q) {
      cvB[(row * 16 + tx) * 5 + q] = tv[r][q];
      ciB[(row * 16 + tx) * 5 + q] = ti[r][q];
    }
  }
  __syncthreads();
  if (tid < RT) {
    const int row = tid;
    float mv[5]; int mi[5];
    #pragma unroll
    for (int q = 0; q < 5; ++q) { mv[q] = 3.0e38f; mi[q] = 0x7fffffff; }
    for (int j = 0; j < 80; ++j) {
      INS5L(mv, mi, cvB[row * 80 + j], ciB[row * 80 + j]);
    }
    const size_t o = ((size_t)(rowBase + row) * NCHUNK + blockIdx.y) * Kk;
    #pragma unroll
    for (int q = 0; q < 5; ++q) { candV[o + q] = mv[q]; candI[o + q] = mi[q]; }
  }
}

// Kernel 4: final 16-chunk merge -> gather-mean -> mobius_add -> f32 out.
// x (z_hyp) is read back from the z_hyp output region.
__global__ __launch_bounds__(128) void k_fuse(
    const float* __restrict__ emb, const float* __restrict__ candV,
    const int* __restrict__ candI, const float* __restrict__ zhyp,
    float* __restrict__ out)
{
  __shared__ int sidx[Kk];
  __shared__ float red[6];
  const int row = blockIdx.x;
  const int tid = threadIdx.x;
  if (tid == 0) {
    float mv[5]; int mi[5];
    #pragma unroll
    for (int q = 0; q < 5; ++q) { mv[q] = 3.0e38f; mi[q] = 0x7fffffff; }
    const size_t base = (size_t)row * NCHUNK * Kk;
    for (int j = 0; j < NCHUNK * Kk; ++j) {
      INS5L(mv, mi, candV[base + j], candI[base + j]);
    }
    #pragma unroll
    for (int q = 0; q < 5; ++q) sidx[q] = mi[q];
  }
  __syncthreads();
  float y = 0.f;
  #pragma unroll
  for (int q = 0; q < Kk; ++q) y += emb[(size_t)sidx[q] * Dd + tid];
  y = y / 5.0f;
  const float x = zhyp[(size_t)row * Dd + tid];
  float x2 = x * x, y2 = y * y, xy = x * y;
  #pragma unroll
  for (int off = 32; off > 0; off >>= 1) {
    x2 += __shfl_xor(x2, off);
    y2 += __shfl_xor(y2, off);
    xy += __shfl_xor(xy, off);
  }
  const int wv = tid >> 6, ln = tid & 63;
  if (ln == 0) { red[wv * 3 + 0] = x2; red[wv * 3 + 1] = y2; red[wv * 3 + 2] = xy; }
  __syncthreads();
  x2 = red[0] + red[3]; y2 = red[1] + red[4]; xy = red[2] + red[5];
  const float num = (1.f + 2.f * xy + y2) * x + (1.f - x2) * y;
  const float den = 1.f + 2.f * xy + x2 * y2;
  out[(size_t)row * Dd + tid] = num / (den + EPSF);
}

extern "C" void kernel_launch(void* const* d_in, const int* in_sizes, int n_in,
                              void* d_out, int out_size, void* d_ws, size_t ws_size,
                              hipStream_t stream)
{
  (void)in_sizes; (void)n_in; (void)out_size; (void)ws_size;
  const float* zseq = (const float*)d_in[0];
  const float* emb  = (const float*)d_in[1];
  const float* W    = (const float*)d_in[2];
  const float* bias = (const float*)d_in[3];
  float* out = (float*)d_out;            // [z_fused (B*D) | z_hyp (B*D)] f32

  float* ws    = (float*)d_ws;
  float* zt    = ws;                 // B*D f32 tangent vectors
  float* sArr  = zt + HALF;          // N
  float* cArr  = sArr + Nn;          // N
  float* candV = cArr + Nn;          // B*NCHUNK*K
  int*   candI = (int*)(candV + (size_t)Bb * NCHUNK * Kk);

  hipLaunchKernelGGL(k_proj, dim3(Bb / 8), dim3(128), 0, stream,
                     zseq, W, bias, out + HALF, zt);
  hipLaunchKernelGGL(k_node, dim3(Nn / 4), dim3(256), 0, stream, emb, sArr, cArr);
  hipLaunchKernelGGL(k_topk, dim3(16, 16), dim3(256), 0, stream,
                     zt, emb, sArr, cArr, candV, candI);
  hipLaunchKernelGGL(k_fuse, dim3(Bb), dim3(128), 0, stream,
                     emb, candV, candI, out + HALF, out);
}

// Round 3
// 389.345 us; speedup vs baseline: 3.3836x; 3.3836x over previous
//
#include <hip/hip_runtime.h>
#include <hip/hip_bf16.h>
#include <math.h>

#define EPSF 1e-7f
#define MAXT 0.99999f   // 1 - 1e-5

typedef __attribute__((ext_vector_type(8))) short short8v;   // 8 x bf16 (4 VGPR)
typedef __attribute__((ext_vector_type(4))) float f32x4;     // MFMA C/D frag

constexpr int Bb = 2048;
constexpr int Ss = 768;
constexpr int Dd = 128;
constexpr int Nn = 100000;
constexpr int Kk = 5;
constexpr int HALF = Bb * Dd;        // 262144
constexpr int NCHUNK = 16;
constexpr int CHUNK = Nn / NCHUNK;   // 6250
constexpr int RT = 128;              // rows per topk block
constexpr int NT = 128;              // nodes per tile
constexpr int NTILES = (CHUNK + NT - 1) / NT;  // 49 (last tile 106 valid)

static __device__ __forceinline__ ushort f2bf(float x) {
  __hip_bfloat16 h = __float2bfloat16(x);
  return *reinterpret_cast<ushort*>(&h);
}

// Insert into ascending-sorted top-5 (strict <: keeps earliest/lowest idx on tie).
#define INS5(TV, TI, V, ID) do { \
  const float _v = (V); const int _id = (ID); \
  if (_v < TV[4]) { \
    TV[4] = _v; TI[4] = _id; \
    if (TV[4] < TV[3]) { float _t=TV[3];TV[3]=TV[4];TV[4]=_t;int _u=TI[3];TI[3]=TI[4];TI[4]=_u; } \
    if (TV[3] < TV[2]) { float _t=TV[2];TV[2]=TV[3];TV[3]=_t;int _u=TI[2];TI[2]=TI[3];TI[3]=_u; } \
    if (TV[2] < TV[1]) { float _t=TV[1];TV[1]=TV[2];TV[2]=_t;int _u=TI[1];TI[1]=TI[2];TI[2]=_u; } \
    if (TV[1] < TV[0]) { float _t=TV[0];TV[0]=TV[1];TV[1]=_t;int _u=TI[0];TI[0]=TI[1];TI[1]=_u; } \
  } } while(0)

// Lexicographic (value, index) insert for merging unordered candidate streams.
#define LXLT(V,I,V2,I2) ((V) < (V2) || ((V) == (V2) && (I) < (I2)))
#define INS5L(TV, TI, V, ID) do { \
  const float _v = (V); const int _id = (ID); \
  if (LXLT(_v,_id,TV[4],TI[4])) { \
    TV[4]=_v; TI[4]=_id; \
    if (LXLT(TV[4],TI[4],TV[3],TI[3])) { float _t=TV[3];TV[3]=TV[4];TV[4]=_t;int _u=TI[3];TI[3]=TI[4];TI[4]=_u; } \
    if (LXLT(TV[3],TI[3],TV[2],TI[2])) { float _t=TV[2];TV[2]=TV[3];TV[3]=_t;int _u=TI[2];TI[2]=TI[3];TI[3]=_u; } \
    if (LXLT(TV[2],TI[2],TV[1],TI[1])) { float _t=TV[1];TV[1]=TV[2];TV[2]=_t;int _u=TI[1];TI[1]=TI[2];TI[2]=_u; } \
    if (LXLT(TV[1],TI[1],TV[0],TI[0])) { float _t=TV[0];TV[0]=TV[1];TV[1]=_t;int _u=TI[0];TI[0]=TI[1];TI[1]=_u; } \
  } } while(0)

// Kernel 1: z_proj = z_seq @ W.T + b; z_hyp = expmap0 -> out[HALF..] (f32);
// z_tan = logmap0(z_hyp) -> ztb (bf16, MFMA A operand).
__global__ __launch_bounds__(128) void k_proj(
    const float* __restrict__ zseq, const float* __restrict__ W,
    const float* __restrict__ bias, float* __restrict__ outH,
    ushort* __restrict__ ztb)
{
  __shared__ __align__(16) float zrow[8][768];
  __shared__ float zp[8][128];
  __shared__ float rno[8];
  const int tid = threadIdx.x;
  const int r0 = blockIdx.x * 8;

  {
    const float4* src = reinterpret_cast<const float4*>(zseq + (size_t)r0 * Ss);
    float4* dst = reinterpret_cast<float4*>(&zrow[0][0]);
    #pragma unroll
    for (int i = 0; i < 12; ++i) dst[i * 128 + tid] = src[i * 128 + tid];
  }
  __syncthreads();

  float acc[8];
  const float bv = bias[tid];
  #pragma unroll
  for (int r = 0; r < 8; ++r) acc[r] = bv;
  const float4* w4 = reinterpret_cast<const float4*>(W + (size_t)tid * Ss);
  for (int j = 0; j < Ss / 4; ++j) {
    const float4 w = w4[j];
    #pragma unroll
    for (int r = 0; r < 8; ++r) {
      const float4 z = *reinterpret_cast<const float4*>(&zrow[r][j * 4]);
      acc[r] = fmaf(z.x, w.x, acc[r]);
      acc[r] = fmaf(z.y, w.y, acc[r]);
      acc[r] = fmaf(z.z, w.z, acc[r]);
      acc[r] = fmaf(z.w, w.w, acc[r]);
    }
  }
  #pragma unroll
  for (int r = 0; r < 8; ++r) zp[r][tid] = acc[r];
  __syncthreads();

  const int wv = tid >> 6, ln = tid & 63;
  #pragma unroll
  for (int rr = 0; rr < 4; ++rr) {
    const int r = wv * 4 + rr;
    float v = zp[r][ln] * zp[r][ln] + zp[r][ln + 64] * zp[r][ln + 64];
    #pragma unroll
    for (int off = 32; off > 0; off >>= 1) v += __shfl_xor(v, off);
    if (ln == 0) rno[r] = v;
  }
  __syncthreads();

  #pragma unroll
  for (int r = 0; r < 8; ++r) {
    const float n = fmaxf(sqrtf(rno[r]), EPSF);
    const float zh = tanhf(n) * zp[r][tid] / n;
    outH[(size_t)(r0 + r) * Dd + tid] = zh;   // z_hyp output (f32)
    zp[r][tid] = zh;
  }
  __syncthreads();
  #pragma unroll
  for (int rr = 0; rr < 4; ++rr) {
    const int r = wv * 4 + rr;
    float v = zp[r][ln] * zp[r][ln] + zp[r][ln + 64] * zp[r][ln + 64];
    #pragma unroll
    for (int off = 32; off > 0; off >>= 1) v += __shfl_xor(v, off);
    if (ln == 0) rno[r] = v;
  }
  __syncthreads();
  #pragma unroll
  for (int r = 0; r < 8; ++r) {
    const float m = fmaxf(sqrtf(rno[r]), EPSF);
    const float a = atanhf(fminf(m, MAXT));
    ztb[(size_t)(r0 + r) * Dd + tid] = f2bf(a * zp[r][tid] / m);
  }
}

// Kernel 2: per-node logmap0 scalars: s_n = atanh(clip(||e||))/||e||, c_n = ||n_tan||^2.
__global__ __launch_bounds__(256) void k_node(
    const float* __restrict__ emb, float* __restrict__ sArr, float* __restrict__ cArr)
{
  const int wv = threadIdx.x >> 6, ln = threadIdx.x & 63;
  const int node = blockIdx.x * 4 + wv;
  const float2 v = *reinterpret_cast<const float2*>(emb + (size_t)node * Dd + ln * 2);
  float t = v.x * v.x + v.y * v.y;
  #pragma unroll
  for (int off = 32; off > 0; off >>= 1) t += __shfl_xor(t, off);
  if (ln == 0) {
    const float E = fmaxf(sqrtf(t), EPSF);
    const float a = atanhf(fminf(E, MAXT));
    const float s = a / E;
    sArr[node] = s;
    cArr[node] = s * s * t;
  }
}

// Kernel 3: bf16-MFMA score GEMM + fused top-5.
// Block = 128 rows x 6250-node chunk; 8 waves = 4 row-groups x 2 col-groups.
// score_n = c_n - 2*s_n*(z_tan . emb_n)  (rank-equivalent to reference d2).
__global__ __launch_bounds__(512, 2) void k_topk(
    const ushort* __restrict__ ztb, const float* __restrict__ emb,
    const float* __restrict__ sArr, const float* __restrict__ cArr,
    float* __restrict__ candV, int* __restrict__ candI)
{
  __shared__ __align__(16) ushort Bsm[2][NT * Dd];   // 2 x 32KB, XOR-swizzled bf16
  __shared__ __align__(16) float2 sclb[2][NT];       // (s_n, c_n)
  __shared__ __align__(16) float mgv[RT][2][Kk];     // cross-wave merge buffers
  __shared__ int mgi[RT][2][Kk];

  const int tid = threadIdx.x;
  const int ln = tid & 63;
  const int wv = tid >> 6;       // 0..7
  const int ln15 = ln & 15;
  const int g = ln >> 4;         // 0..3
  const int wr = wv >> 1;        // row-group 0..3 (32 rows each)
  const int wc = wv & 1;         // col-group 0..1 (64 cols each)
  const int rowBase = blockIdx.x * RT;
  const int chunkStart = blockIdx.y * CHUNK;

  // A fragments in registers, reused across all 49 tiles:
  // row = rowBase + 32*wr + 16*f + (lane&15); k = 32*ks + 8*(lane>>4)
  short8v afr[2][4];
  #pragma unroll
  for (int f = 0; f < 2; ++f)
    #pragma unroll
    for (int ks = 0; ks < 4; ++ks)
      afr[f][ks] = *reinterpret_cast<const short8v*>(
          ztb + (size_t)(rowBase + 32 * wr + 16 * f + ln15) * Dd + 32 * ks + 8 * g);

  // per-lane swizzled LDS byte offsets for B-frag reads (+ c*4096 immediate)
  int rdoff[4];
  #pragma unroll
  for (int ks = 0; ks < 4; ++ks)
    rdoff[ks] = (wc * 64 + ln15) * 256 + ((g * 16 + ks * 64) ^ ((ln15 & 7) << 4));

  f32x4 acc[2][4];
  #pragma unroll
  for (int f = 0; f < 2; ++f)
    #pragma unroll
    for (int c = 0; c < 4; ++c) acc[f][c] = (f32x4)0.f;

  float tv[8][5]; int ti[8][5];
  #pragma unroll
  for (int r = 0; r < 8; ++r)
    #pragma unroll
    for (int q = 0; q < 5; ++q) { tv[r][q] = 3.0e38f; ti[r][q] = 0x7fffffff; }

  float4 ld[8];   // in-flight staging registers (T14 split)

  auto stageLoad = [&](int t) {
    const int tStart = t * NT;
    const int left = CHUNK - tStart;
    #pragma unroll
    for (int i = 0; i < 8; ++i) {
      const int flat = i * 512 + tid;        // float4 index within tile
      const int nd = flat >> 5;              // node 0..127
      float4 v = make_float4(0.f, 0.f, 0.f, 0.f);
      if (nd < left)
        v = *reinterpret_cast<const float4*>(
            emb + (size_t)(chunkStart + tStart + nd) * Dd + (flat & 31) * 4);
      ld[i] = v;
    }
  };

  auto stageWrite = [&](int t, int buf) {
    char* base = reinterpret_cast<char*>(&Bsm[buf][0]);
    #pragma unroll
    for (int i = 0; i < 8; ++i) {
      const int flat = i * 512 + tid;
      const int nd = flat >> 5;
      const int kb = (flat & 31) * 8;        // byte offset of 4 bf16 within row
      ushort4 w;
      w.x = f2bf(ld[i].x); w.y = f2bf(ld[i].y);
      w.z = f2bf(ld[i].z); w.w = f2bf(ld[i].w);
      *reinterpret_cast<ushort4*>(base + nd * 256 + (kb ^ ((nd & 7) << 4))) = w;
    }
    const int tStart = t * NT;
    const int left = CHUNK - tStart;
    if (tid < NT) {
      const bool ok = tid < left;
      sclb[buf][tid] = make_float2(ok ? sArr[chunkStart + tStart + tid] : 0.f,
                                   ok ? cArr[chunkStart + tStart + tid] : 3.0e38f);
    }
  };

  stageLoad(0);
  stageWrite(0, 0);
  __syncthreads();

  for (int t = 0; t < NTILES; ++t) {
    const int buf = t & 1;
    const bool have = (t + 1) < NTILES;
    if (have) stageLoad(t + 1);              // issue early: latency hides under MFMA

    const char* bbase = reinterpret_cast<const char*>(&Bsm[buf][0]);
    #pragma unroll
    for (int c = 0; c < 4; ++c) {
      #pragma unroll
      for (int ks = 0; ks < 4; ++ks) {
        const short8v bfr = *reinterpret_cast<const short8v*>(bbase + c * 4096 + rdoff[ks]);
        acc[0][c] = __builtin_amdgcn_mfma_f32_16x16x32_bf16(afr[0][ks], bfr, acc[0][c], 0, 0, 0);
        acc[1][c] = __builtin_amdgcn_mfma_f32_16x16x32_bf16(afr[1][ks], bfr, acc[1][c], 0, 0, 0);
      }
    }

    if (have) stageWrite(t + 1, buf ^ 1);    // write late into the other buffer

    // epilogue: scores + per-lane top-5 (8 rows/lane, 4 nodes each)
    #pragma unroll
    for (int c = 0; c < 4; ++c) {
      const int nl = wc * 64 + c * 16 + ln15;
      const float2 sc2 = sclb[buf][nl];
      const int node = chunkStart + t * NT + nl;
      const float m2s = -2.f * sc2.x;
      #pragma unroll
      for (int f = 0; f < 2; ++f) {
        #pragma unroll
        for (int i = 0; i < 4; ++i) {
          const float v = fmaf(m2s, acc[f][c][i], sc2.y);
          INS5(tv[f * 4 + i], ti[f * 4 + i], v, node);
        }
        acc[f][c] = (f32x4)0.f;
      }
    }
    __syncthreads();
  }

  // butterfly merge across the 16 lanes sharing each row set
  #pragma unroll
  for (int m = 1; m <= 8; m <<= 1) {
    #pragma unroll
    for (int r = 0; r < 8; ++r) {
      float ov[5]; int oi[5];
      #pragma unroll
      for (int q = 0; q < 5; ++q) {
        ov[q] = __shfl_xor(tv[r][q], m);
        oi[q] = __shfl_xor(ti[r][q], m);
      }
      #pragma unroll
      for (int q = 0; q < 5; ++q) INS5L(tv[r], ti[r], ov[q], oi[q]);
    }
  }
  if (ln15 == 0) {
    #pragma unroll
    for (int f = 0; f < 2; ++f)
      #pragma unroll
      for (int i = 0; i < 4; ++i) {
        const int row = 32 * wr + 16 * f + 4 * g + i;
        #pragma unroll
        for (int q = 0; q < 5; ++q) {
          mgv[row][wc][q] = tv[f * 4 + i][q];
          mgi[row][wc][q] = ti[f * 4 + i][q];
        }
      }
  }
  __syncthreads();
  if (tid < RT) {
    float mv[5]; int mi[5];
    #pragma unroll
    for (int q = 0; q < 5; ++q) { mv[q] = mgv[tid][0][q]; mi[q] = mgi[tid][0][q]; }
    #pragma unroll
    for (int q = 0; q < 5; ++q) INS5L(mv, mi, mgv[tid][1][q], mgi[tid][1][q]);
    const size_t o = ((size_t)(rowBase + tid) * NCHUNK + blockIdx.y) * Kk;
    #pragma unroll
    for (int q = 0; q < 5; ++q) { candV[o + q] = mv[q]; candI[o + q] = mi[q]; }
  }
}

// Kernel 4: final 16-chunk merge -> gather-mean -> mobius_add -> f32 out.
__global__ __launch_bounds__(128) void k_fuse(
    const float* __restrict__ emb, const float* __restrict__ candV,
    const int* __restrict__ candI, const float* __restrict__ zhyp,
    float* __restrict__ out)
{
  __shared__ int sidx[Kk];
  __shared__ float red[6];
  const int row = blockIdx.x;
  const int tid = threadIdx.x;
  if (tid == 0) {
    float mv[5]; int mi[5];
    #pragma unroll
    for (int q = 0; q < 5; ++q) { mv[q] = 3.0e38f; mi[q] = 0x7fffffff; }
    const size_t base = (size_t)row * NCHUNK * Kk;
    for (int j = 0; j < NCHUNK * Kk; ++j) {
      INS5L(mv, mi, candV[base + j], candI[base + j]);
    }
    #pragma unroll
    for (int q = 0; q < 5; ++q) sidx[q] = mi[q];
  }
  __syncthreads();
  float y = 0.f;
  #pragma unroll
  for (int q = 0; q < Kk; ++q) y += emb[(size_t)sidx[q] * Dd + tid];
  y = y / 5.0f;
  const float x = zhyp[(size_t)row * Dd + tid];
  float x2 = x * x, y2 = y * y, xy = x * y;
  #pragma unroll
  for (int off = 32; off > 0; off >>= 1) {
    x2 += __shfl_xor(x2, off);
    y2 += __shfl_xor(y2, off);
    xy += __shfl_xor(xy, off);
  }
  const int wv = tid >> 6, ln = tid & 63;
  if (ln == 0) { red[wv * 3 + 0] = x2; red[wv * 3 + 1] = y2; red[wv * 3 + 2] = xy; }
  __syncthreads();
  x2 = red[0] + red[3]; y2 = red[1] + red[4]; xy = red[2] + red[5];
  const float num = (1.f + 2.f * xy + y2) * x + (1.f - x2) * y;
  const float den = 1.f + 2.f * xy + x2 * y2;
  out[(size_t)row * Dd + tid] = num / (den + EPSF);
}

extern "C" void kernel_launch(void* const* d_in, const int* in_sizes, int n_in,
                              void* d_out, int out_size, void* d_ws, size_t ws_size,
                              hipStream_t stream)
{
  (void)in_sizes; (void)n_in; (void)out_size; (void)ws_size;
  const float* zseq = (const float*)d_in[0];
  const float* emb  = (const float*)d_in[1];
  const float* W    = (const float*)d_in[2];
  const float* bias = (const float*)d_in[3];
  float* out = (float*)d_out;            // [z_fused (B*D) | z_hyp (B*D)] f32

  ushort* ztb  = (ushort*)d_ws;                       // B*D bf16 tangent vectors
  float* sArr  = (float*)(ztb + (size_t)Bb * Dd);     // N
  float* cArr  = sArr + Nn;                           // N
  float* candV = cArr + Nn;                           // B*NCHUNK*K
  int*   candI = (int*)(candV + (size_t)Bb * NCHUNK * Kk);

  hipLaunchKernelGGL(k_proj, dim3(Bb / 8), dim3(128), 0, stream,
                     zseq, W, bias, out + HALF, ztb);
  hipLaunchKernelGGL(k_node, dim3(Nn / 4), dim3(256), 0, stream, emb, sArr, cArr);
  hipLaunchKernelGGL(k_topk, dim3(16, 16), dim3(512), 0, stream,
                     ztb, emb, sArr, cArr, candV, candI);
  hipLaunchKernelGGL(k_fuse, dim3(Bb), dim3(128), 0, stream,
                     emb, candV, candI, out + HALF, out);
}